// Round 5
// baseline (7196.870 us; speedup 1.0000x reference)
//
#include <hip/hip_runtime.h>
#include <hip/hip_bf16.h>

#define T_SEQ 512
#define NBATCH 64
#define HID 300
#define G4 1200
#define NTAG 11
#define TAG_START 9
#define TAG_STOP 10
#define NEGV -10000.0f
#define NWGD 19             // lstm WGs per direction, 16 hidden units (= 2 kblocks) each
#define NKT 10              // k-tiles of 32 (K padded 300->320)
#define HXE (40*2*64*8)     // u16 per (dir,pp) hx buffer: 40 kblocks x {hi,lo} x 64 b x 8
#define NPREW 150           // companion pregemm WGs
#define FLGS 16             // u32 stride between flags (64B slots)
#define FLGN 76             // flags per dir = 19 WGs x 4 waves
#define FLGDIR (FLGN*FLGS)

typedef unsigned short u16;
using short8 = __attribute__((ext_vector_type(8))) short;
using f32x4  = __attribute__((ext_vector_type(4))) float;
using i32x4  = __attribute__((ext_vector_type(4))) int;

#define MF(a, b, c) __builtin_amdgcn_mfma_f32_16x16x32_bf16((a), (b), (c), 0, 0, 0)

__device__ __forceinline__ float sigf(float x) { return 1.0f / (1.0f + expf(-x)); }

__device__ __forceinline__ u16 f2bf(float x) {
    unsigned u = __float_as_uint(x);
    unsigned r = (u + 0x7FFFu + ((u >> 16) & 1u)) >> 16;   // RNE
    return (u16)r;
}
__device__ __forceinline__ float bf2f(u16 h) {
    return __uint_as_float((unsigned)h << 16);
}

// ---- LLC-coherent (fabric point) helpers: sc0 sc1, no cache-maintenance ops ----
__device__ __forceinline__ i32x4 ld_cc_x4(const u16* p) {
    i32x4 r;
    asm volatile("global_load_dwordx4 %0, %1, off sc0 sc1" : "=v"(r) : "v"(p) : "memory");
    return r;
}
__device__ __forceinline__ unsigned ld_cc_b32(const unsigned* p) {
    unsigned r;
    asm volatile("global_load_dword %0, %1, off sc0 sc1\n\t"
                 "s_waitcnt vmcnt(0)" : "=v"(r) : "v"(p) : "memory");
    return r;
}
__device__ __forceinline__ void st_cc_x4(u16* p, i32x4 v) {
    asm volatile("global_store_dwordx4 %0, %1, off sc0 sc1" :: "v"(p), "v"(v) : "memory");
}
__device__ __forceinline__ void st_cc_b32(unsigned* p, unsigned v) {
    asm volatile("global_store_dword %0, %1, off sc0 sc1" :: "v"(p), "v"(v) : "memory");
}
__device__ __forceinline__ void wait_vm0() {
    asm volatile("s_waitcnt vmcnt(0)" ::: "memory");
}

// ---------- embedding gather -> block layout xs0[t][40][64][2][8] (hi8|lo8 u16) ----------
__global__ __launch_bounds__(256) void k_gather(const int* __restrict__ x,
                                                const float* __restrict__ emb,
                                                u16* __restrict__ xs0)
{
    int t = blockIdx.x;
    __shared__ int rid[NBATCH];
    if (threadIdx.x < NBATCH) rid[threadIdx.x] = x[threadIdx.x * T_SEQ + t];
    __syncthreads();
    for (int o = threadIdx.x; o < 64 * 40; o += 256) {
        int b = o / 40, m8 = o - b * 40;
        unsigned hw[4], lw[4];
#pragma unroll
        for (int p = 0; p < 4; ++p) {
            int k0 = m8 * 8 + p * 2;
            float v0 = (k0 < 300)     ? emb[(size_t)rid[b] * 300 + k0]     : 0.0f;
            float v1 = (k0 + 1 < 300) ? emb[(size_t)rid[b] * 300 + k0 + 1] : 0.0f;
            u16 h0 = f2bf(v0), h1 = f2bf(v1);
            u16 l0 = f2bf(v0 - bf2f(h0)), l1 = f2bf(v1 - bf2f(h1));
            hw[p] = (unsigned)h0 | ((unsigned)h1 << 16);
            lw[p] = (unsigned)l0 | ((unsigned)l1 << 16);
        }
        u16* dst = xs0 + (((size_t)t * 40 + m8) * 64 + b) * 16;
        *(i32x4*)dst       = i32x4{(int)hw[0], (int)hw[1], (int)hw[2], (int)hw[3]};
        *(i32x4*)(dst + 8) = i32x4{(int)lw[0], (int)lw[1], (int)lw[2], (int)lw[3]};
    }
}

// ---------- zero xs1 pad blocks 76..79 ----------
__global__ __launch_bounds__(256) void k_zpad(u16* __restrict__ xs1)
{
    int t = blockIdx.x;
    i32x4* base = (i32x4*)(xs1 + (((size_t)t * 80 + 76) * 64) * 16);
    i32x4 z = {0, 0, 0, 0};
    for (int o = threadIdx.x; o < 4 * 64 * 2; o += 256) base[o] = z;
}

// ---------- pregemm core (device): one (jtile,dir), timesteps [s0,s1) ----------
template<int KT, int KMAX>
__device__ __forceinline__ void pregemm_role(
    const u16* __restrict__ xs,
    const float* __restrict__ Wi, const float* __restrict__ bi, const float* __restrict__ bh,
    float* __restrict__ pre, int jtile, int dir, int t0f, int t0b, int s0, int s1, int tid)
{
    int w = tid >> 6, l = tid & 63;
    int hh = l >> 4, kbx = l >> 4;
    int jj = jtile * 4 + hh;
    int bcol = w * 16 + (l & 15);

    short8 aH[KT], aL[KT];
    {
        int r = l & 15;
        int g = r & 3, uo = r >> 2;
        const float* wr = Wi + ((size_t)g * 300 + jtile * 4 + uo) * KMAX;
        int kb0 = kbx * 8;
#pragma unroll
        for (int kt = 0; kt < KT; ++kt) {
            short8 vh, vl;
#pragma unroll
            for (int e = 0; e < 8; ++e) {
                int kp = kt * 32 + kb0 + e;
                bool valid; int cc;
                if (KMAX == 600) { valid = (kp < 300) || (kp >= 304 && kp < 604); cc = (kp < 300) ? kp : kp - 4; }
                else             { valid = (kp < 300); cc = kp; }
                float wv = valid ? wr[cc] : 0.0f;
                u16 hb = f2bf(wv);
                vh[e] = (short)hb;
                vl[e] = (short)f2bf(wv - bf2f(hb));
            }
            aH[kt] = vh; aL[kt] = vl;
        }
    }
    float bias[4];
#pragma unroll
    for (int q = 0; q < 4; ++q) bias[q] = bi[q * 300 + jj] + bh[q * 300 + jj];

    const int NB8 = KT * 4;
    for (int s = s0; s < s1; ++s) {
        int t = dir ? (t0b - s) : (t0f + s);
        f32x4 a0 = {0.f,0.f,0.f,0.f}, a1 = {0.f,0.f,0.f,0.f}, a2 = {0.f,0.f,0.f,0.f};
#pragma unroll
        for (int kt = 0; kt < KT; ++kt) {
            const u16* gx = xs + (((size_t)t * NB8 + (4 * kt + kbx)) * 64 + bcol) * 16;
            short8 bhv = *(const short8*)gx;
            short8 blv = *(const short8*)(gx + 8);
            a0 = MF(aH[kt], bhv, a0);
            a1 = MF(aL[kt], bhv, a1);
            a2 = MF(aH[kt], blv, a2);
        }
#pragma unroll
        for (int q = 0; q < 4; ++q)
            pre[((size_t)s * G4 + q * 300 + jj) * 64 + bcol] = a0[q] + a1[q] + a2[q] + bias[q];
    }
}

// ---------- standalone pregemm (chunk 0 of each layer): sliced grid ----------
template<int KT, int KMAX>
__global__ __launch_bounds__(256) void k_pregemm(
    const u16* __restrict__ xs,
    const float* __restrict__ WiF, const float* __restrict__ WiB,
    const float* __restrict__ biF, const float* __restrict__ bhF,
    const float* __restrict__ biB, const float* __restrict__ bhB,
    float* __restrict__ preF, float* __restrict__ preB,
    int t0f, int t0b, int NSL, int C)
{
    int bx = blockIdx.x;
    int idx = bx / (2 * NSL);
    int rem = bx - idx * 2 * NSL;
    int sl = rem >> 1, dir = rem & 1;
    int s0 = sl * 32, s1 = min(s0 + 32, C);
    pregemm_role<KT, KMAX>(xs,
        dir ? WiB : WiF, dir ? biB : biF, dir ? bhB : bhF,
        dir ? preB : preF, idx, dir, t0f, t0b, s0, s1, threadIdx.x);
}

// ---------- lstm role: 16 j per WG (19 WGs/dir), halved coherent exchange ----------
// hx per (dir,pp): [kblock 0..39][plane hi/lo][batch 0..63][8 u16], UNCHANGED.
// Each WG owns 16 j = 2 hx kblocks {2idx, 2idx+1}; exchange READ volume per
// dir per step drops 38x80KB -> 19x80KB (the J-fan-out broadcast halves).
// A_hi fragments (4 stripes x 10 kt) stay in registers; A_lo streams from a
// 40KB LDS image filled once per chunk (off-fabric, conflict-free lane-order
// fragments). Flags: per (idx,wave) = 76/dir, 64B-strided single-writer
// lines; round-3 proven sharded poll (wave w polls flags [19w,19w+19), one
// lane each, LDS monotone combine).
template<int MODE>
__device__ __forceinline__ void lstm_role(
    const float* __restrict__ preF, const float* __restrict__ preB,
    const float* __restrict__ WhF, const float* __restrict__ WhB,
    u16* __restrict__ hx, float* __restrict__ cbuf,
    float* __restrict__ xs2, u16* __restrict__ xs1,
    int t0f, int t0b, int C, int first,
    unsigned* __restrict__ flags,
    char* __restrict__ alo, volatile unsigned* wgprog,
    int bid, int tid)
{
    __builtin_amdgcn_s_setprio(1);
    int dir = bid & 1, idx = bid >> 1;   // idx 0..18
    const float* pre = dir ? preB : preF;
    const float* Wh  = dir ? WhB : WhF;
    u16* hxd = hx + (size_t)dir * 2 * HXE;
    float* cb = cbuf + (size_t)dir * 300 * 64;
    unsigned* flg = flags + (size_t)dir * FLGDIR;
    int w = tid >> 6, l = tid & 63;
    int hh = l >> 4, kbx = l >> 4;
    int bcol = w * 16 + (l & 15);
    int j0 = idx * 16;
    int blk0 = idx * 2, blk1 = idx * 2 + 1;

    int ju[4], jc[4]; bool jv[4];
#pragma unroll
    for (int q = 0; q < 4; ++q) {
        ju[q] = j0 + q * 4 + hh;
        jc[q] = min(ju[q], 299);
        jv[q] = ju[q] < 300;
    }

    unsigned* myflag = flg + (size_t)(idx * 4 + w) * FLGS;
    // shard poll: wave w covers flags [19w, 19w+19), lane i -> flag 19w+i
    const unsigned* shardp = flg + (size_t)(w * 19 + min(l, 18)) * FLGS;
    bool shact = l < 19;

    // A_hi fragments (4 stripes) in registers; A_lo -> LDS (wave w fills stripe w)
    short8 aH[4][NKT];
    {
        int r = l & 15;
        int g = r & 3, uo = r >> 2;
#pragma unroll
        for (int q = 0; q < 4; ++q) {
            int jr = j0 + q * 4 + uo;
            const float* wr = Wh + ((size_t)g * 300 + min(jr, 299)) * 300;
            bool jvr = jr < 300;
#pragma unroll
            for (int kt = 0; kt < NKT; ++kt) {
                short8 vh, vl;
#pragma unroll
                for (int e = 0; e < 8; ++e) {
                    int k = kt * 32 + kbx * 8 + e;
                    float wv = (jvr && k < 300) ? wr[k] : 0.0f;
                    u16 hb = f2bf(wv);
                    vh[e] = (short)hb;
                    vl[e] = (short)f2bf(wv - bf2f(hb));
                }
                aH[q][kt] = vh;
                if (q == w)
                    *(short8*)(alo + ((size_t)(q * NKT + kt) * 1024) + (size_t)l * 16) = vl;
            }
        }
    }
    if (l == 0) wgprog[w] = 0;
    __syncthreads();   // A_lo image + wgprog ready (one-time)

    float c[4];
#pragma unroll
    for (int q = 0; q < 4; ++q) c[q] = first ? 0.0f : cb[(size_t)jc[q] * 64 + bcol];

    float p[4][4];
#pragma unroll
    for (int q = 0; q < 4; ++q)
#pragma unroll
        for (int g = 0; g < 4; ++g)
            p[q][g] = pre[((size_t)g * 300 + jc[q]) * 64 + bcol];

    int pp = 0;
    for (int s = 0; s < C; ++s) {
        f32x4 z = {0.f,0.f,0.f,0.f};
        f32x4 aA[4] = {z, z, z, z}, aB[4] = {z, z, z, z}, aC[4] = {z, z, z, z};
        if (!(first && s == 0)) {
            const u16* hxr = hxd + (size_t)pp * HXE;
            i32x4 bh[NKT], bl[NKT];
#pragma unroll
            for (int kt = 0; kt < NKT; ++kt) {
                const u16* gp = hxr + (size_t)(4 * kt + kbx) * 1024 + (size_t)bcol * 8;
                bh[kt] = ld_cc_x4(gp);
            }
#pragma unroll
            for (int kt = 0; kt < NKT; ++kt) {
                const u16* gp = hxr + (size_t)(4 * kt + kbx) * 1024 + (size_t)bcol * 8;
                bl[kt] = ld_cc_x4(gp + 512);
            }
            // hi plane ready (10 lo still in flight)
            asm volatile("s_waitcnt vmcnt(10)" ::: "memory");
            __builtin_amdgcn_sched_barrier(0);
#pragma unroll
            for (int kt = 0; kt < NKT; ++kt) {
                short8 bhv = __builtin_bit_cast(short8, bh[kt]);
#pragma unroll
                for (int q = 0; q < 4; ++q)
                    aA[q] = MF(aH[q][kt], bhv, aA[q]);
#pragma unroll
                for (int q = 0; q < 4; ++q) {
                    short8 alv = *(const short8*)(alo + ((size_t)(q * NKT + kt) * 1024) + (size_t)l * 16);
                    aB[q] = MF(alv, bhv, aB[q]);
                }
            }
            wait_vm0();
            __builtin_amdgcn_sched_barrier(0);
#pragma unroll
            for (int kt = 0; kt < NKT; ++kt) {
                short8 blv = __builtin_bit_cast(short8, bl[kt]);
#pragma unroll
                for (int q = 0; q < 4; ++q)
                    aC[q] = MF(aH[q][kt], blv, aC[q]);
            }
        }
        float hv[4]; unsigned pk[4];
#pragma unroll
        for (int q = 0; q < 4; ++q) {
            float gi = sigf(aA[q][0] + aB[q][0] + aC[q][0] + p[q][0]);
            float gf = sigf(aA[q][1] + aB[q][1] + aC[q][1] + p[q][1]);
            float gg = tanhf(aA[q][2] + aB[q][2] + aC[q][2] + p[q][2]);
            float go = sigf(aA[q][3] + aB[q][3] + aC[q][3] + p[q][3]);
            c[q] = gf * c[q] + gi * gg;
            float h = go * tanhf(c[q]);
            if (!jv[q]) h = 0.0f;
            hv[q] = h;
            u16 hb = f2bf(h);
            pk[q] = (unsigned)hb | ((unsigned)f2bf(h - bf2f(hb)) << 16);
        }
        int ls = l & 15;
        unsigned q0a = __shfl(pk[0], ls), q0b = __shfl(pk[0], ls + 16), q0c = __shfl(pk[0], ls + 32), q0d = __shfl(pk[0], ls + 48);
        unsigned q1a = __shfl(pk[1], ls), q1b = __shfl(pk[1], ls + 16), q1c = __shfl(pk[1], ls + 32), q1d = __shfl(pk[1], ls + 48);
        unsigned q2a = __shfl(pk[2], ls), q2b = __shfl(pk[2], ls + 16), q2c = __shfl(pk[2], ls + 32), q2d = __shfl(pk[2], ls + 48);
        unsigned q3a = __shfl(pk[3], ls), q3b = __shfl(pk[3], ls + 16), q3c = __shfl(pk[3], ls + 32), q3d = __shfl(pk[3], ls + 48);
        i32x4 hi4_0 = {(int)((q0a & 0xffffu) | (q0b << 16)), (int)((q0c & 0xffffu) | (q0d << 16)),
                       (int)((q1a & 0xffffu) | (q1b << 16)), (int)((q1c & 0xffffu) | (q1d << 16))};
        i32x4 lo4_0 = {(int)((q0a >> 16) | (q0b & 0xffff0000u)), (int)((q0c >> 16) | (q0d & 0xffff0000u)),
                       (int)((q1a >> 16) | (q1b & 0xffff0000u)), (int)((q1c >> 16) | (q1d & 0xffff0000u))};
        i32x4 hi4_1 = {(int)((q2a & 0xffffu) | (q2b << 16)), (int)((q2c & 0xffffu) | (q2d << 16)),
                       (int)((q3a & 0xffffu) | (q3b << 16)), (int)((q3c & 0xffffu) | (q3d << 16))};
        i32x4 lo4_1 = {(int)((q2a >> 16) | (q2b & 0xffff0000u)), (int)((q2c >> 16) | (q2d & 0xffff0000u)),
                       (int)((q3a >> 16) | (q3b & 0xffff0000u)), (int)((q3c >> 16) | (q3d & 0xffff0000u))};
        int t = dir ? (t0b - s) : (t0f + s);
        i32x4 h4 = (l < 16) ? hi4_0 : hi4_1;
        i32x4 l4 = (l < 16) ? lo4_0 : lo4_1;
        int blkS = (l < 16) ? blk0 : blk1;
        int bb = w * 16 + ls;
        // exchange stores (lanes 0-15 -> blk0, 16-31 -> blk1), wave drain, own flag
        if (l < 32) {
            u16* hxw = hxd + (size_t)(pp ^ 1) * HXE + (size_t)blkS * 1024 + (size_t)bb * 8;
            st_cc_x4(hxw, h4);
            st_cc_x4(hxw + 512, l4);
        }
        wait_vm0();
        if (l == 0) st_cc_b32(myflag, (unsigned)(s + 1));
        // xs output + next-step pre prefetch (drain under the poll)
        if (MODE == 0) {
#pragma unroll
            for (int q = 0; q < 4; ++q)
                if (jv[q]) xs2[((size_t)t * 600 + dir * 300 + ju[q]) * 64 + bcol] = hv[q];
        } else if (l < 32) {
            u16* xd = xs1 + (((size_t)t * 80 + dir * 38 + blkS) * 64 + bb) * 16;
            *(i32x4*)xd       = h4;
            *(i32x4*)(xd + 8) = l4;
        }
        if (s + 1 < C) {
#pragma unroll
            for (int q = 0; q < 4; ++q)
#pragma unroll
                for (int g = 0; g < 4; ++g)
                    p[q][g] = pre[((size_t)(s + 1) * G4 + (size_t)g * 300 + jc[q]) * 64 + bcol];
            unsigned tgt = (unsigned)(s + 1);
            unsigned ok;
            do {
                unsigned v = tgt;
                if (shact) v = ld_cc_b32(shardp);
                ok = (v >= tgt) ? 1u : 0u;
            } while (!__all(ok));
            if (l == 0) wgprog[w] = tgt;
            while (!(wgprog[0] >= tgt && wgprog[1] >= tgt &&
                     wgprog[2] >= tgt && wgprog[3] >= tgt)) {
                __builtin_amdgcn_s_sleep(1);
            }
        }
        pp ^= 1;
    }
#pragma unroll
    for (int q = 0; q < 4; ++q)
        if (jv[q]) cb[(size_t)jc[q] * 64 + bcol] = c[q];
}

// ---------- fused chunk kernel: 38 lstm WGs + 150 companion pregemm WGs ----------
template<int KT, int KMAX, int MODE>
__global__ __launch_bounds__(256, 1) void k_chunk(
    const u16* __restrict__ xsN,
    const float* __restrict__ WiF, const float* __restrict__ WiB,
    const float* __restrict__ biF, const float* __restrict__ bhF,
    const float* __restrict__ biB, const float* __restrict__ bhB,
    float* __restrict__ preNF, float* __restrict__ preNB,
    int t0fN, int t0bN, int do_pre, int CN,
    const float* __restrict__ preF, const float* __restrict__ preB,
    const float* __restrict__ WhF, const float* __restrict__ WhB,
    u16* __restrict__ hx, float* __restrict__ cbuf,
    float* __restrict__ xs2, u16* __restrict__ xs1,
    int t0f, int t0b, int C, int first,
    unsigned* __restrict__ flags)
{
    __shared__ __align__(16) char smem[40 * 1024 + 64];
    int bid = blockIdx.x;
    if (bid < 2 * NWGD) {
        lstm_role<MODE>(preF, preB, WhF, WhB, hx, cbuf, xs2, xs1,
                        t0f, t0b, C, first, flags,
                        smem, (volatile unsigned*)(smem + 40 * 1024),
                        bid, threadIdx.x);
    } else if (do_pre) {
        int wg = bid - 2 * NWGD;         // 0..149
        int jtile = wg >> 1, dir = wg & 1;
        pregemm_role<KT, KMAX>(xsN,
            dir ? WiB : WiF, dir ? biB : biF, dir ? bhB : bhF,
            dir ? preNB : preNF, jtile, dir, t0fN, t0bN, 0, CN, threadIdx.x);
    }
}

// ---------- output projection: feats[t][g][b] ----------
__global__ __launch_bounds__(256) void k_feats(
    const float* __restrict__ xs2, const float* __restrict__ Wout,
    const float* __restrict__ bout, float* __restrict__ feats)
{
    int t = blockIdx.x;
    int tid = threadIdx.x;
    int b = tid & 63, g0 = tid >> 6;
    const float* xa = xs2 + (size_t)t * 600 * 64 + b;
    for (int g = g0; g < NTAG; g += 4) {
        float acc = bout[g];
        const float* wr = Wout + (size_t)g * 600;
#pragma unroll 4
        for (int k = 0; k < 600; ++k) acc += wr[k] * xa[(size_t)k * 64];
        feats[((size_t)t * NTAG + g) * 64 + b] = acc;
    }
}

// ---------- Viterbi ----------
__global__ __launch_bounds__(256) void k_viterbi(
    const float* __restrict__ feats, const float* __restrict__ trans,
    float* __restrict__ out)
{
    __shared__ unsigned char bp[4][T_SEQ * NTAG];
    int tid = threadIdx.x;
    int wv = tid >> 6, lane = tid & 63;
    int b = blockIdx.x * 4 + wv;
    int i = (lane < NTAG) ? lane : 0;
    bool act = lane < NTAG;
    float trow[NTAG];
#pragma unroll
    for (int j = 0; j < NTAG; ++j) trow[j] = trans[i * NTAG + j];
    float fv = (lane == TAG_START) ? 0.0f : NEGV;
    for (int t = 0; t < T_SEQ; ++t) {
        float m = -3.0e38f; int arg = 0;
#pragma unroll
        for (int j = 0; j < NTAG; ++j) {
            float fvj = __shfl(fv, j, 64);
            float sc = fvj + trow[j];
            if (sc > m) { m = sc; arg = j; }
        }
        float ft = feats[((size_t)t * NTAG + i) * 64 + b];
        fv = m + ft;
        if (act) bp[wv][t * NTAG + lane] = (unsigned char)arg;
    }
    float term = act ? (fv + trans[TAG_STOP * NTAG + i]) : -3.0e38f;
    int bi_ = lane;
#pragma unroll
    for (int off = 32; off >= 1; off >>= 1) {
        float ov = __shfl_xor(term, off, 64);
        int oi = __shfl_xor(bi_, off, 64);
        if (ov > term || (ov == term && oi < bi_)) { term = ov; bi_ = oi; }
    }
    if (lane == 0) {
        out[b] = term;
        int tag = bi_;
        float* po = out + 64 + (size_t)b * T_SEQ;
        for (int t = T_SEQ - 1; t >= 0; --t) {
            po[t] = (float)tag;
            tag = bp[wv][t * NTAG + tag];
        }
    }
}

extern "C" void kernel_launch(void* const* d_in, const int* in_sizes, int n_in,
                              void* d_out, int out_size, void* d_ws, size_t ws_size,
                              hipStream_t stream)
{
    (void)in_sizes; (void)n_in; (void)out_size;
    const int*   x     = (const int*)d_in[0];
    const float* emb   = (const float*)d_in[1];
    const float* Wout  = (const float*)d_in[2];
    const float* bout  = (const float*)d_in[3];
    const float* trans = (const float*)d_in[4];

    float* ws = (float*)d_ws;
    const size_t XS2F = (size_t)T_SEQ * 600 * NBATCH;          // f32
    const size_t XS1U = (size_t)T_SEQ * 80 * 64 * 16;          // u16
    const size_t FEA  = (size_t)T_SEQ * NTAG * NBATCH;

    float* xs2 = ws;                          // layer-1 f32 output (aliases xs0 blocks)
    u16* xs0 = (u16*)ws;                      // [T][40][64][2][8]
    u16* xs1 = (u16*)(ws + XS2F);             // [T][80][64][2][8]
    float* featB = (float*)(xs1 + XS1U);
    float* cB = featB + FEA;                  // 2*300*64
    u16* hxB = (u16*)(cB + 2 * 300 * 64);     // 4*HXE
    unsigned* flagsB = (unsigned*)(hxB + 4 * HXE);   // 64 slots * 2 dirs * FLGDIR
    unsigned* padB = flagsB + 64ULL * 2 * FLGDIR;    // layout hole kept (16 u32)
    float* preBase = (float*)(padB + 16);
    size_t fixedBytes = (size_t)((char*)preBase - (char*)ws);

    // two ping-pong pre slots; each slot = preF+preB = 2*Cmax*G4*64 floats
    int Cmax = 512;
    while (Cmax > 16 && fixedBytes + 4ULL * Cmax * G4 * NBATCH * 4ULL > ws_size) Cmax >>= 1;
    size_t slotF = 2ULL * Cmax * G4 * NBATCH;
    float* preS[2] = { preBase, preBase + slotF };

    // chunk schedule: small first chunk shrinks the exposed standalone pregemm
    int sizes[40], off[41], nch = 0;
    {
        int rem = T_SEQ;
        int f = (Cmax >= 64) ? 32 : Cmax;
        sizes[nch++] = f; rem -= f;
        while (rem > 0) { int s = rem < Cmax ? rem : Cmax; sizes[nch++] = s; rem -= s; }
        off[0] = 0;
        for (int i = 0; i < nch; ++i) off[i + 1] = off[i] + sizes[i];
    }

    (void)hipMemsetAsync(hxB, 0,
        4 * HXE * sizeof(u16) + (64ULL * 2 * FLGDIR) * sizeof(unsigned), stream);
    k_gather<<<T_SEQ, 256, 0, stream>>>(x, emb, xs0);
    k_zpad<<<T_SEQ, 256, 0, stream>>>(xs1);

    for (int layer = 0; layer < 2; ++layer) {
        int base = 5 + layer * 8;
        const float* WiF = (const float*)d_in[base + 0];
        const float* WhF = (const float*)d_in[base + 1];
        const float* biF = (const float*)d_in[base + 2];
        const float* bhF = (const float*)d_in[base + 3];
        const float* WiB = (const float*)d_in[base + 4];
        const float* WhB = (const float*)d_in[base + 5];
        const float* biB = (const float*)d_in[base + 6];
        const float* bhB = (const float*)d_in[base + 7];

        int NSL0 = (sizes[0] + 31) / 32;
        if (layer == 0)
            k_pregemm<10, 300><<<75 * 2 * NSL0, 256, 0, stream>>>(
                xs0, WiF, WiB, biF, bhF, biB, bhB,
                preS[0], preS[0] + slotF / 2, 0, T_SEQ - 1, NSL0, sizes[0]);
        else
            k_pregemm<20, 600><<<75 * 2 * NSL0, 256, 0, stream>>>(
                xs1, WiF, WiB, biF, bhF, biB, bhB,
                preS[0], preS[0] + slotF / 2, 0, T_SEQ - 1, NSL0, sizes[0]);

        for (int ci = 0; ci < nch; ++ci) {
            int cur = ci & 1, nxt = cur ^ 1;
            int t0f = off[ci], t0b = (T_SEQ - 1) - off[ci];
            int do_pre = (ci + 1 < nch) ? 1 : 0;
            int CN = do_pre ? sizes[ci + 1] : 0;
            int t0fN = off[ci + 1], t0bN = (T_SEQ - 1) - off[ci + 1];
            int slot = layer * 32 + ci;
            unsigned* flags = flagsB + (size_t)slot * 2 * FLGDIR;
            if (layer == 0)
                k_chunk<10, 300, 1><<<2 * NWGD + NPREW, 256, 0, stream>>>(
                    xs0, WiF, WiB, biF, bhF, biB, bhB,
                    preS[nxt], preS[nxt] + slotF / 2, t0fN, t0bN, do_pre, CN,
                    preS[cur], preS[cur] + slotF / 2, WhF, WhB, hxB, cB,
                    xs2, xs1, t0f, t0b, sizes[ci], (ci == 0) ? 1 : 0, flags);
            else
                k_chunk<20, 600, 0><<<2 * NWGD + NPREW, 256, 0, stream>>>(
                    xs1, WiF, WiB, biF, bhF, biB, bhB,
                    preS[nxt], preS[nxt] + slotF / 2, t0fN, t0bN, do_pre, CN,
                    preS[cur], preS[cur] + slotF / 2, WhF, WhB, hxB, cB,
                    xs2, xs1, t0f, t0b, sizes[ci], (ci == 0) ? 1 : 0, flags);
        }
    }
    k_feats<<<T_SEQ, 256, 0, stream>>>(xs2, Wout, bout, featB);
    k_viterbi<<<16, 256, 0, stream>>>(featB, trans, (float*)d_out);
}